// Round 4
// baseline (236.290 us; speedup 1.0000x reference)
//
#include <hip/hip_runtime.h>
#include <hip/hip_bf16.h>
#include <cstdint>

#define N_SRC 100000
#define N_DST 25000
#define N_EDGE 300000
// D_IN = D_HID = D_OUT = 256, concat K = 512

typedef float f32x4 __attribute__((ext_vector_type(4)));
typedef __bf16 bf16x8 __attribute__((ext_vector_type(8)));

__device__ __forceinline__ unsigned short f2bf(float f) {
    union { float f; unsigned int u; } v; v.f = f;
    unsigned int u = v.u;
    u += 0x7FFFu + ((u >> 16) & 1u);   // RNE; inputs finite
    return (unsigned short)(u >> 16);
}
__device__ __forceinline__ float bf2f(unsigned int bits16) {
    union { unsigned int u; float f; } v; v.u = bits16 << 16;
    return v.f;
}

// ---- cast + transpose weights: Qt[n][k] = bf16(Q_w[k][n]), Wt[n][k] = bf16(W_w[k][n])
__global__ void cast_weights(const float* __restrict__ Qw, const float* __restrict__ Ww,
                             unsigned short* __restrict__ Qt, unsigned short* __restrict__ Wt) {
    int i = blockIdx.x * blockDim.x + threadIdx.x;
    if (i < 256 * 256) {
        int n = i >> 8, k = i & 255;
        Qt[n * 256 + k] = f2bf(Qw[k * 256 + n]);
    } else if (i < 256 * 256 + 512 * 256) {
        int j = i - 256 * 256;
        int n = j >> 9, k = j & 511;
        Wt[n * 512 + k] = f2bf(Ww[k * 256 + n]);
    }
}

// ---- CSR build
__global__ void hist_kernel(const int* __restrict__ dst_idx, int* __restrict__ counts) {
    int i = blockIdx.x * blockDim.x + threadIdx.x;
    if (i < N_EDGE) atomicAdd(&counts[dst_idx[i]], 1);
}

__global__ __launch_bounds__(1024) void scan_kernel(const int* __restrict__ counts,
                                                    int* __restrict__ offsets, int n) {
    __shared__ int wsum[16];
    const int t = threadIdx.x;
    const int wid = t >> 6, lane = t & 63;
    int carry = 0;
    if (t == 0) offsets[0] = 0;
    for (int base = 0; base < n; base += 1024) {
        int x = (base + t < n) ? counts[base + t] : 0;
        #pragma unroll
        for (int off = 1; off < 64; off <<= 1) {
            int y = __shfl_up(x, off, 64);
            if (lane >= off) x += y;
        }
        if (lane == 63) wsum[wid] = x;
        __syncthreads();
        if (t < 16) {
            int w = wsum[t];
            #pragma unroll
            for (int off = 1; off < 16; off <<= 1) {
                int y = __shfl_up(w, off, 64);
                if (t >= off) w += y;
            }
            wsum[t] = w;
        }
        __syncthreads();
        int pre = (wid > 0) ? wsum[wid - 1] : 0;
        int incl = carry + pre + x;
        if (base + t < n) offsets[base + t + 1] = incl;
        carry += wsum[15];
        __syncthreads();
    }
}

__global__ void scatter_kernel(const int* __restrict__ dst_idx, const int* __restrict__ offsets,
                               int* __restrict__ counts, int* __restrict__ edge_list) {
    int i = blockIdx.x * blockDim.x + threadIdx.x;
    if (i < N_EDGE) {
        int d = dst_idx[i];
        int pos = offsets[d] + (atomicSub(&counts[d], 1) - 1);
        edge_list[pos] = i;
    }
}

// ---- GEMM1: nft = relu(h_src @ Qt^T + Qb), bf16 out.
// Wave-independent: each wave owns 32 rows x 128 cols. No LDS, no barriers.
// A (f32, HBM) prefetched 2 k-tiles ahead into a 3-slot register ring;
// B (bf16, 128KB, L2-resident) loaded per k-tile.
__global__ __launch_bounds__(256, 3) void gemm1_wave(
    const float* __restrict__ Af, const unsigned short* __restrict__ Bt,
    const float* __restrict__ bias, unsigned short* __restrict__ Cb)
{
    const int gw = blockIdx.x * 4 + (threadIdx.x >> 6);
    const int mt = gw >> 1, nt = gw & 1;
    if (mt >= 3125) return;                    // 3125*32 = 100000 exact
    const int lane = threadIdx.x & 63, g = lane >> 4, cl = lane & 15;
    const int m0 = mt * 32, n0 = nt * 128;

    f32x4 acc[2][8];
    #pragma unroll
    for (int mi = 0; mi < 2; ++mi)
        #pragma unroll
        for (int ni = 0; ni < 8; ++ni)
            acc[mi][ni] = (f32x4){0.f, 0.f, 0.f, 0.f};

    float4 Ar[3][2][2];   // [slot][mi][half]
    uint4  Br[8];

    auto loadA = [&](int slot, int kt) {
        #pragma unroll
        for (int mi = 0; mi < 2; ++mi) {
            const float* p = Af + (size_t)(m0 + mi * 16 + cl) * 256 + kt * 32 + g * 8;
            Ar[slot][mi][0] = *reinterpret_cast<const float4*>(p);
            Ar[slot][mi][1] = *reinterpret_cast<const float4*>(p + 4);
        }
    };
    loadA(0, 0);
    loadA(1, 1);

    #pragma unroll
    for (int kt = 0; kt < 8; ++kt) {
        #pragma unroll
        for (int ni = 0; ni < 8; ++ni)
            Br[ni] = *reinterpret_cast<const uint4*>(
                Bt + (size_t)(n0 + ni * 16 + cl) * 256 + kt * 32 + g * 8);
        if (kt + 2 < 8) loadA((kt + 2) % 3, kt + 2);
        #pragma unroll
        for (int mi = 0; mi < 2; ++mi) {
            const float4 lo = Ar[kt % 3][mi][0];
            const float4 hi = Ar[kt % 3][mi][1];
            bf16x8 af;
            af[0] = (__bf16)lo.x; af[1] = (__bf16)lo.y; af[2] = (__bf16)lo.z; af[3] = (__bf16)lo.w;
            af[4] = (__bf16)hi.x; af[5] = (__bf16)hi.y; af[6] = (__bf16)hi.z; af[7] = (__bf16)hi.w;
            #pragma unroll
            for (int ni = 0; ni < 8; ++ni)
                acc[mi][ni] = __builtin_amdgcn_mfma_f32_16x16x32_bf16(
                    af, __builtin_bit_cast(bf16x8, Br[ni]), acc[mi][ni], 0, 0, 0);
        }
    }

    float bcol[8];
    #pragma unroll
    for (int ni = 0; ni < 8; ++ni) bcol[ni] = bias[n0 + ni * 16 + cl];

    #pragma unroll
    for (int mi = 0; mi < 2; ++mi) {
        const int rowb = m0 + mi * 16 + g * 4;
        #pragma unroll
        for (int ni = 0; ni < 8; ++ni) {
            const int col = n0 + ni * 16 + cl;
            #pragma unroll
            for (int r = 0; r < 4; ++r) {
                float v = fmaxf(acc[mi][ni][r] + bcol[ni], 0.f);
                Cb[(size_t)(rowb + r) * 256 + col] = f2bf(v);
            }
        }
    }
}

// ---- GEMM2: out = rownorm(relu(xb @ Wt^T + Wb)), f32 out.
// Wave = 32 rows x 128 cols; block = 2 row-groups x 2 n-tiles. Only barrier is
// the epilogue norm exchange between the two n-tile waves of a row-group.
__global__ __launch_bounds__(256, 3) void gemm2_wave(
    const unsigned short* __restrict__ Ab, const unsigned short* __restrict__ Bt,
    const float* __restrict__ bias, float* __restrict__ Cf, int M)
{
    __shared__ float norml[4][32];
    const int wv = threadIdx.x >> 6;
    const int gw = blockIdx.x * 2 + (wv >> 1);   // row-tile id (0..781)
    const int nt = wv & 1;
    const int lane = threadIdx.x & 63, g = lane >> 4, cl = lane & 15;
    const int m0 = gw * 32, n0 = nt * 128;

    f32x4 acc[2][8];
    #pragma unroll
    for (int mi = 0; mi < 2; ++mi)
        #pragma unroll
        for (int ni = 0; ni < 8; ++ni)
            acc[mi][ni] = (f32x4){0.f, 0.f, 0.f, 0.f};

    uint4 Ar[3][2];
    uint4 Br[8];

    auto loadA = [&](int slot, int kt) {
        #pragma unroll
        for (int mi = 0; mi < 2; ++mi) {
            int row = m0 + mi * 16 + cl; if (row > M - 1) row = M - 1;
            Ar[slot][mi] = *reinterpret_cast<const uint4*>(
                Ab + (size_t)row * 512 + kt * 32 + g * 8);
        }
    };
    loadA(0, 0);
    loadA(1, 1);

    #pragma unroll
    for (int kt = 0; kt < 16; ++kt) {
        #pragma unroll
        for (int ni = 0; ni < 8; ++ni)
            Br[ni] = *reinterpret_cast<const uint4*>(
                Bt + (size_t)(n0 + ni * 16 + cl) * 512 + kt * 32 + g * 8);
        if (kt + 2 < 16) loadA((kt + 2) % 3, kt + 2);
        #pragma unroll
        for (int mi = 0; mi < 2; ++mi) {
            const bf16x8 af = __builtin_bit_cast(bf16x8, Ar[kt % 3][mi]);
            #pragma unroll
            for (int ni = 0; ni < 8; ++ni)
                acc[mi][ni] = __builtin_amdgcn_mfma_f32_16x16x32_bf16(
                    af, __builtin_bit_cast(bf16x8, Br[ni]), acc[mi][ni], 0, 0, 0);
        }
    }

    float bcol[8];
    #pragma unroll
    for (int ni = 0; ni < 8; ++ni) bcol[ni] = bias[n0 + ni * 16 + cl];

    float ssq[2][4];
    #pragma unroll
    for (int mi = 0; mi < 2; ++mi) {
        #pragma unroll
        for (int r = 0; r < 4; ++r) {
            float s = 0.f;
            #pragma unroll
            for (int ni = 0; ni < 8; ++ni) {
                float v = fmaxf(acc[mi][ni][r] + bcol[ni], 0.f);
                acc[mi][ni][r] = v;
                s += v * v;
            }
            #pragma unroll
            for (int m = 1; m < 16; m <<= 1) s += __shfl_xor(s, m, 64);
            ssq[mi][r] = s;
        }
    }
    if (cl == 0) {
        #pragma unroll
        for (int mi = 0; mi < 2; ++mi)
            #pragma unroll
            for (int r = 0; r < 4; ++r)
                norml[wv][mi * 16 + g * 4 + r] = ssq[mi][r];
    }
    __syncthreads();
    #pragma unroll
    for (int mi = 0; mi < 2; ++mi) {
        #pragma unroll
        for (int r = 0; r < 4; ++r) {
            const int rl = mi * 16 + g * 4 + r;
            const float tot = norml[wv][rl] + norml[wv ^ 1][rl];
            const float rn = tot > 0.f ? rsqrtf(tot) : 1.0f;
            const int row = m0 + rl;
            if (row < M) {
                #pragma unroll
                for (int ni = 0; ni < 8; ++ni)
                    Cf[(size_t)row * 256 + n0 + ni * 16 + cl] = acc[mi][ni][r] * rn;
            }
        }
    }
}

// ---- per-dst aggregation: one wave per dst; unroll-2 on edges
__global__ __launch_bounds__(256) void aggregate_kernel(
    const unsigned short* __restrict__ nft, const float* __restrict__ h_dst,
    const float* __restrict__ weights, const int* __restrict__ src_idx,
    const int* __restrict__ edge_list, const int* __restrict__ offsets,
    unsigned short* __restrict__ xb)
{
    int d = blockIdx.x * 4 + (threadIdx.x >> 6);
    if (d >= N_DST) return;
    int lane = threadIdx.x & 63;
    int p0 = offsets[d], p1 = offsets[d + 1];
    float a0 = 0.f, a1 = 0.f, a2 = 0.f, a3 = 0.f, wsum = 0.f;
    int p = p0;
    for (; p + 1 < p1; p += 2) {
        int e0 = edge_list[p], e1 = edge_list[p + 1];
        float w0 = weights[e0], w1 = weights[e1];
        int s0 = src_idx[e0], s1 = src_idx[e1];
        uint2 v0 = *reinterpret_cast<const uint2*>(nft + (size_t)s0 * 256 + lane * 4);
        uint2 v1 = *reinterpret_cast<const uint2*>(nft + (size_t)s1 * 256 + lane * 4);
        wsum += w0 + w1;
        a0 += w0 * bf2f(v0.x & 0xffffu) + w1 * bf2f(v1.x & 0xffffu);
        a1 += w0 * bf2f(v0.x >> 16)     + w1 * bf2f(v1.x >> 16);
        a2 += w0 * bf2f(v0.y & 0xffffu) + w1 * bf2f(v1.y & 0xffffu);
        a3 += w0 * bf2f(v0.y >> 16)     + w1 * bf2f(v1.y >> 16);
    }
    if (p < p1) {
        int e = edge_list[p];
        float w = weights[e];
        int s = src_idx[e];
        wsum += w;
        uint2 v = *reinterpret_cast<const uint2*>(nft + (size_t)s * 256 + lane * 4);
        a0 += w * bf2f(v.x & 0xffffu);
        a1 += w * bf2f(v.x >> 16);
        a2 += w * bf2f(v.y & 0xffffu);
        a3 += w * bf2f(v.y >> 16);
    }
    float inv = 1.0f / fmaxf(wsum, 1.0f);
    uint2 pk;
    pk.x = (unsigned)f2bf(a0 * inv) | ((unsigned)f2bf(a1 * inv) << 16);
    pk.y = (unsigned)f2bf(a2 * inv) | ((unsigned)f2bf(a3 * inv) << 16);
    *reinterpret_cast<uint2*>(xb + (size_t)d * 512 + lane * 4) = pk;
    float4 h = *reinterpret_cast<const float4*>(h_dst + (size_t)d * 256 + lane * 4);
    uint2 q;
    q.x = (unsigned)f2bf(h.x) | ((unsigned)f2bf(h.y) << 16);
    q.y = (unsigned)f2bf(h.z) | ((unsigned)f2bf(h.w) << 16);
    *reinterpret_cast<uint2*>(xb + (size_t)d * 512 + 256 + lane * 4) = q;
}

extern "C" void kernel_launch(void* const* d_in, const int* in_sizes, int n_in,
                              void* d_out, int out_size, void* d_ws, size_t ws_size,
                              hipStream_t stream) {
    const float* h_src   = (const float*)d_in[0];
    const float* h_dst   = (const float*)d_in[1];
    const float* weights = (const float*)d_in[2];
    const float* Q_w     = (const float*)d_in[3];
    const float* Q_b     = (const float*)d_in[4];
    const float* W_w     = (const float*)d_in[5];
    const float* W_b     = (const float*)d_in[6];
    const int* src_idx   = (const int*)d_in[7];
    const int* dst_idx   = (const int*)d_in[8];
    float* out = (float*)d_out;

    char* ws = (char*)d_ws;
    unsigned short* nft = (unsigned short*)(ws);               // 51,200,000
    unsigned short* xb  = (unsigned short*)(ws + 51200000);    // 25,600,000
    unsigned short* Qt  = (unsigned short*)(ws + 76800000);    // 131,072
    unsigned short* Wt  = (unsigned short*)(ws + 76931072);    // 262,144
    int* counts    = (int*)(ws + 77193216);                    // 100,000
    int* offsets   = (int*)(ws + 77293216);                    // 100,004
    int* edge_list = (int*)(ws + 77393220);                    // 1,200,000 (~78.6 MB)

    hipMemsetAsync(counts, 0, N_DST * sizeof(int), stream);

    cast_weights<<<768, 256, 0, stream>>>(Q_w, W_w, Qt, Wt);
    hist_kernel<<<(N_EDGE + 255) / 256, 256, 0, stream>>>(dst_idx, counts);
    scan_kernel<<<1, 1024, 0, stream>>>(counts, offsets, N_DST);
    scatter_kernel<<<(N_EDGE + 255) / 256, 256, 0, stream>>>(dst_idx, offsets, counts, edge_list);

    // 6250 waves (3125 row-tiles x 2 n-tiles), 4 waves/block
    gemm1_wave<<<1563, 256, 0, stream>>>(h_src, Qt, Q_b, nft);

    aggregate_kernel<<<N_DST / 4, 256, 0, stream>>>(
        nft, h_dst, weights, src_idx, edge_list, offsets, xb);

    // 782 row-tiles x 2 n-tiles = 1564 waves, 4 waves/block
    gemm2_wave<<<391, 256, 0, stream>>>(xb, Wt, W_b, out, N_DST);

    (void)in_sizes; (void)n_in; (void)out_size; (void)ws_size;
}